// Round 6
// baseline (3921.898 us; speedup 1.0000x reference)
//
#include <hip/hip_runtime.h>
#include <hip/hip_bf16.h>
#include <stdint.h>

#define T_NUM 1024
#define H_DIM 2048
#define E_NUM 16
#define TOPK 4
#define I_DIM 1408
#define SHI_DIM 2816

typedef __attribute__((ext_vector_type(4))) float f32x4;
typedef __attribute__((ext_vector_type(8))) short bf16x8;
typedef __attribute__((ext_vector_type(4))) short s16x4;

static __device__ __forceinline__ short f2bf(float f) {
    __hip_bfloat16 h = __float2bfloat16(f);
    return __builtin_bit_cast(short, h);
}
static __device__ __forceinline__ float bf2f(short s) {
    return __bfloat162float(__builtin_bit_cast(__hip_bfloat16, s));
}

// ---------------- router: fp32 logits -> softmax -> top4 (+ x -> bf16) ------
__global__ void router_kernel(const float* __restrict__ x, const float* __restrict__ wgate,
                              int* __restrict__ top_e, float* __restrict__ top_w,
                              short* __restrict__ xb) {
    const int t = blockIdx.x;
    const int tid = threadIdx.x;       // 256 threads
    __shared__ float xsh[H_DIM];
    const float* xr = x + (size_t)t * H_DIM;
    for (int h = tid; h < H_DIM; h += 256) xsh[h] = xr[h];
    __syncthreads();

    {   // bf16 copy of x
        short v[8];
        #pragma unroll
        for (int i = 0; i < 8; ++i) v[i] = f2bf(xsh[tid * 8 + i]);
        *reinterpret_cast<bf16x8*>(xb + (size_t)t * H_DIM + tid * 8) = *(bf16x8*)v;
    }

    const int e = tid >> 4;            // 0..15
    const int j = tid & 15;
    const float* wr = wgate + (size_t)e * H_DIM;
    float acc = 0.f;
    for (int h = j; h < H_DIM; h += 16) acc += xsh[h] * wr[h];
    #pragma unroll
    for (int m = 8; m >= 1; m >>= 1) acc += __shfl_down(acc, m, 16);

    __shared__ float logits[E_NUM];
    if (j == 0) logits[e] = acc;
    __syncthreads();

    if (tid == 0) {
        float mx = logits[0];
        #pragma unroll
        for (int i = 1; i < E_NUM; ++i) mx = fmaxf(mx, logits[i]);
        float p[E_NUM]; float s = 0.f;
        #pragma unroll
        for (int i = 0; i < E_NUM; ++i) { p[i] = expf(logits[i] - mx); s += p[i]; }
        const float inv = 1.f / s;
        #pragma unroll
        for (int i = 0; i < E_NUM; ++i) p[i] *= inv;
        for (int k = 0; k < TOPK; ++k) {
            float best = -1.f; int bi = 0;
            #pragma unroll
            for (int i = 0; i < E_NUM; ++i) if (p[i] > best) { best = p[i]; bi = i; }
            top_e[t * TOPK + k] = bi;
            top_w[t * TOPK + k] = best;
            p[bi] = -2.f;
        }
    }
}

// ------- stable bucket sort of 4096 slots by expert (deterministic) -------
__global__ void perm_kernel(const int* __restrict__ top_e,
                            int* __restrict__ offs, int* __restrict__ perm) {
    __shared__ int cnt[256][E_NUM];
    __shared__ int base[E_NUM];
    const int tid = threadIdx.x;
    int c[E_NUM];
    #pragma unroll
    for (int i = 0; i < E_NUM; ++i) c[i] = 0;
    for (int s = tid * 16; s < tid * 16 + 16; ++s) c[top_e[s]]++;
    #pragma unroll
    for (int i = 0; i < E_NUM; ++i) cnt[tid][i] = c[i];
    __syncthreads();
    if (tid < E_NUM) {
        int run = 0;
        for (int b = 0; b < 256; ++b) { int v = cnt[b][tid]; cnt[b][tid] = run; run += v; }
        base[tid] = run;
    }
    __syncthreads();
    if (tid == 0) {
        int run = 0;
        for (int e2 = 0; e2 < E_NUM; ++e2) { int v = base[e2]; base[e2] = run; offs[e2] = run; run += v; }
        offs[E_NUM] = run;
    }
    __syncthreads();
    int run[E_NUM];
    #pragma unroll
    for (int i = 0; i < E_NUM; ++i) run[i] = base[i] + cnt[tid][i];
    for (int s = tid * 16; s < tid * 16 + 16; ++s) {
        int e2 = top_e[s];
        perm[run[e2]++] = s;
    }
}

// ------- SwiGLU combine: act = silu(g) * u  (bf16 elementwise) -------
__global__ void swiglu_kernel(const short* __restrict__ g, const short* __restrict__ u,
                              short* __restrict__ act, int n8) {
    const int i = blockIdx.x * 256 + threadIdx.x;
    if (i >= n8) return;
    bf16x8 gv = *reinterpret_cast<const bf16x8*>(g + (size_t)i * 8);
    bf16x8 uv = *reinterpret_cast<const bf16x8*>(u + (size_t)i * 8);
    short o[8];
    #pragma unroll
    for (int j = 0; j < 8; ++j) {
        float gf = bf2f(gv[j]);
        float uf = bf2f(uv[j]);
        o[j] = f2bf(gf / (1.f + __expf(-gf)) * uf);
    }
    *reinterpret_cast<bf16x8*>(act + (size_t)i * 8) = *(bf16x8*)o;
}

// ------- final combine: out[t][h] += sum_k dr[4t+k][h]  (dr pre-weighted) -------
__global__ void combine_kernel(const short* __restrict__ dr, float* __restrict__ out) {
    const int i = blockIdx.x * 256 + threadIdx.x;   // one per 8 cols of a token
    const int t = i >> 8;                            // H_DIM/8 = 256
    const int h8 = (i & 255) * 8;
    float s[8];
    f32x4 o0 = *reinterpret_cast<const f32x4*>(out + (size_t)t * H_DIM + h8);
    f32x4 o1 = *reinterpret_cast<const f32x4*>(out + (size_t)t * H_DIM + h8 + 4);
    #pragma unroll
    for (int j = 0; j < 4; ++j) { s[j] = o0[j]; s[4 + j] = o1[j]; }
    #pragma unroll
    for (int k = 0; k < TOPK; ++k) {
        bf16x8 v = *reinterpret_cast<const bf16x8*>(dr + ((size_t)(t * TOPK + k)) * H_DIM + h8);
        #pragma unroll
        for (int j = 0; j < 8; ++j) s[j] += bf2f(v[j]);
    }
    f32x4 r0 = { s[0], s[1], s[2], s[3] };
    f32x4 r1 = { s[4], s[5], s[6], s[7] };
    *reinterpret_cast<f32x4*>(out + (size_t)t * H_DIM + h8) = r0;
    *reinterpret_cast<f32x4*>(out + (size_t)t * H_DIM + h8 + 4) = r1;
}

// ---------------- GEMM (depth-2 pipeline, NB=1) ----------------
// A: bf16 [rows][K] k-contig. B: f32 [K][N] native (inline convert).
// MODE 0: routed gate|up : A=xb gathered; ntt<nsplit ? wg[e]->Out1 : wu[e]->Out2 (bf16)
// MODE 1: shared gate|up : A=xb dense;    ntt<nsplit ? sg->Out1 : su->Out2 (bf16)
// MODE 2: routed down    : A=act_r gathered; B=wd[e]; store bf16 dr[slot] = w*v
// MODE 3: shared down    : A=act_s dense;    B=sd;    store f32 Out1[row]
template<int MODE>
__global__ __launch_bounds__(256, 3) void gemm_nb1(
    const short* __restrict__ A, int lda, int Kdim,
    const float* __restrict__ B1g, const float* __restrict__ B2g, int ldb,
    void* __restrict__ Out1v, void* __restrict__ Out2v, int ldo,
    const int* __restrict__ perm, const int* __restrict__ offs,
    const float* __restrict__ top_w, int nmt, int nnt, int nsplit)
{
    constexpr int KP = 40;
    __shared__ short As[2][128 * KP];     // 20 KB
    __shared__ short Bs[2][128 * KP];     // 20 KB
    __shared__ int   rows_a[128];
    __shared__ int   rows_o[128];
    __shared__ float w_m[128];

    const int tid = threadIdx.x;

    // bijective XCD swizzle, mt innermost (mt-blocks sharing a B-strip -> same XCD L2)
    int wgid = blockIdx.x;
    {
        const int nwg = gridDim.x;
        const int qq = nwg >> 3, rr = nwg & 7;
        const int xcd = wgid & 7, lin = wgid >> 3;
        wgid = (xcd < rr ? xcd * (qq + 1) : rr * (qq + 1) + (xcd - rr) * qq) + lin;
    }
    const int mt  = wgid % nmt;
    const int ntt = (wgid / nmt) % nnt;
    const int e   = wgid / (nmt * nnt);

    int off = 0, cnt = T_NUM;
    const float* B1 = B1g;
    const float* B2 = B2g;
    if constexpr (MODE == 0) {
        off = offs[e]; cnt = offs[e + 1] - off;
        if (mt * 128 >= cnt) return;
        B1 = B1g + (size_t)e * H_DIM * I_DIM;
        B2 = B2g + (size_t)e * H_DIM * I_DIM;
    }
    if constexpr (MODE == 2) {
        off = offs[e]; cnt = offs[e + 1] - off;
        if (mt * 128 >= cnt) return;
        B1 = B1g + (size_t)e * I_DIM * H_DIM;
    }
    const float* Bsel = (ntt < nsplit) ? B1 : B2;
    const int ncol = (ntt % nsplit) * 128;

    if (tid < 128) {
        const int gm = mt * 128 + tid;
        if constexpr (MODE == 0) {
            int s = perm[off + (gm < cnt ? gm : cnt - 1)];
            rows_a[tid] = s >> 2; rows_o[tid] = s; w_m[tid] = 1.f;
        } else if constexpr (MODE == 2) {
            int s = perm[off + (gm < cnt ? gm : cnt - 1)];
            rows_a[tid] = s; rows_o[tid] = s; w_m[tid] = top_w[s];   // out row = slot
        } else {
            rows_a[tid] = gm; rows_o[tid] = gm; w_m[tid] = 1.f;
        }
    }
    __syncthreads();

    // A row indices in registers (2 rows per thread: m = it*64 + (tid>>2))
    int raReg[2];
    #pragma unroll
    for (int it = 0; it < 2; ++it) raReg[it] = rows_a[it * 64 + (tid >> 2)];

    // two named staging sets (depth-2); NEVER pass these by reference
    bf16x8 aReg0[2], aReg1[2];
    float  bReg0[4][4], bReg1[4][4];

    auto gload0 = [&](int kt) {
        const int k0 = kt * 32;
        #pragma unroll
        for (int it = 0; it < 2; ++it) {
            const int q = it * 256 + tid;
            const int ko = (q & 3) * 8;
            aReg0[it] = *reinterpret_cast<const bf16x8*>(A + (size_t)raReg[it] * lda + k0 + ko);
        }
        #pragma unroll
        for (int it = 0; it < 4; ++it) {
            const int q = it * 256 + tid;
            const int n = q & 127, kb = (q >> 7) * 4;
            const float* p1 = Bsel + (size_t)(k0 + kb) * ldb + ncol + n;
            #pragma unroll
            for (int dk = 0; dk < 4; ++dk) bReg0[it][dk] = p1[(size_t)dk * ldb];
        }
    };
    auto gload1 = [&](int kt) {
        const int k0 = kt * 32;
        #pragma unroll
        for (int it = 0; it < 2; ++it) {
            const int q = it * 256 + tid;
            const int ko = (q & 3) * 8;
            aReg1[it] = *reinterpret_cast<const bf16x8*>(A + (size_t)raReg[it] * lda + k0 + ko);
        }
        #pragma unroll
        for (int it = 0; it < 4; ++it) {
            const int q = it * 256 + tid;
            const int n = q & 127, kb = (q >> 7) * 4;
            const float* p1 = Bsel + (size_t)(k0 + kb) * ldb + ncol + n;
            #pragma unroll
            for (int dk = 0; dk < 4; ++dk) bReg1[it][dk] = p1[(size_t)dk * ldb];
        }
    };

    auto swrite0 = [&]() {   // set0 -> LDS buf 0
        #pragma unroll
        for (int it = 0; it < 2; ++it) {
            const int q = it * 256 + tid;
            const int m = q >> 2, ko = (q & 3) * 8;
            *reinterpret_cast<bf16x8*>(&As[0][m * KP + ko]) = aReg0[it];
        }
        #pragma unroll
        for (int it = 0; it < 4; ++it) {
            const int q = it * 256 + tid;
            const int n = q & 127, kb = (q >> 7) * 4;
            s16x4 v = { f2bf(bReg0[it][0]), f2bf(bReg0[it][1]), f2bf(bReg0[it][2]), f2bf(bReg0[it][3]) };
            *reinterpret_cast<s16x4*>(&Bs[0][n * KP + kb]) = v;
        }
    };
    auto swrite1 = [&]() {   // set1 -> LDS buf 1
        #pragma unroll
        for (int it = 0; it < 2; ++it) {
            const int q = it * 256 + tid;
            const int m = q >> 2, ko = (q & 3) * 8;
            *reinterpret_cast<bf16x8*>(&As[1][m * KP + ko]) = aReg1[it];
        }
        #pragma unroll
        for (int it = 0; it < 4; ++it) {
            const int q = it * 256 + tid;
            const int n = q & 127, kb = (q >> 7) * 4;
            s16x4 v = { f2bf(bReg1[it][0]), f2bf(bReg1[it][1]), f2bf(bReg1[it][2]), f2bf(bReg1[it][3]) };
            *reinterpret_cast<s16x4*>(&Bs[1][n * KP + kb]) = v;
        }
    };

    f32x4 acc[4][4];
    #pragma unroll
    for (int i = 0; i < 4; ++i)
        #pragma unroll
        for (int j = 0; j < 4; ++j) acc[i][j] = (f32x4)0.f;

    const int lane = tid & 63;
    const int wr = (tid >> 7), wc = (tid >> 6) & 1;
    const int lrow = lane & 15;
    const int lko = (lane >> 4) * 8;

    auto compute = [&](int buf) {
        bf16x8 af[4];
        #pragma unroll
        for (int mi = 0; mi < 4; ++mi)
            af[mi] = *reinterpret_cast<const bf16x8*>(&As[buf][(wr * 64 + mi * 16 + lrow) * KP + lko]);
        #pragma unroll
        for (int ni = 0; ni < 4; ++ni) {
            bf16x8 bfr = *reinterpret_cast<const bf16x8*>(&Bs[buf][(wc * 64 + ni * 16 + lrow) * KP + lko]);
            #pragma unroll
            for (int mi = 0; mi < 4; ++mi)
                acc[mi][ni] = __builtin_amdgcn_mfma_f32_16x16x32_bf16(af[mi], bfr, acc[mi][ni], 0, 0, 0);
        }
    };

    const int NK = Kdim / 32;   // 64 / 44 / 88 -- always even
    gload0(0);
    gload1(1);
    for (int kt = 0; kt < NK; kt += 2) {
        swrite0();                       // waits set0 loads only
        __syncthreads();
        if (kt + 2 < NK) gload0(kt + 2); // reissue set0 two tiles ahead
        compute(0);                      // tile kt
        swrite1();                       // waits set1 loads
        __syncthreads();
        if (kt + 3 < NK) gload1(kt + 3);
        compute(1);                      // tile kt+1
    }

    // epilogue
    #pragma unroll
    for (int mi = 0; mi < 4; ++mi) {
        #pragma unroll
        for (int j = 0; j < 4; ++j) {
            const int ml = wr * 64 + mi * 16 + (lane >> 4) * 4 + j;
            const int gm = mt * 128 + ml;
            if constexpr (MODE == 0 || MODE == 2) { if (gm >= cnt) continue; }
            const int orow = (MODE == 0 || MODE == 2) ? rows_o[ml] : gm;
            const float wsc = w_m[ml];
            #pragma unroll
            for (int ni = 0; ni < 4; ++ni) {
                const int n = ncol + wc * 64 + ni * 16 + (lane & 15);
                const float v = acc[mi][ni][j];
                if constexpr (MODE == 0 || MODE == 1) {
                    short* o = (short*)((ntt < nsplit) ? Out1v : Out2v);
                    o[(size_t)orow * ldo + n] = f2bf(v);
                } else if constexpr (MODE == 2) {
                    ((short*)Out1v)[(size_t)orow * ldo + n] = f2bf(v * wsc);
                } else {
                    ((float*)Out1v)[(size_t)orow * ldo + n] = v;
                }
            }
        }
    }
}

extern "C" void kernel_launch(void* const* d_in, const int* in_sizes, int n_in,
                              void* d_out, int out_size, void* d_ws, size_t ws_size,
                              hipStream_t stream) {
    const float* x     = (const float*)d_in[0];
    const float* wgate = (const float*)d_in[1];
    const float* wg    = (const float*)d_in[2];
    const float* wu    = (const float*)d_in[3];
    const float* wd    = (const float*)d_in[4];
    const float* sg    = (const float*)d_in[5];
    const float* su    = (const float*)d_in[6];
    const float* sd    = (const float*)d_in[7];
    float* out = (float*)d_out;

    uintptr_t p = (uintptr_t)d_ws;
    auto alloc = [&](size_t bytes) {
        p = (p + 255) & ~(uintptr_t)255;
        void* r = (void*)p; p += bytes; return r;
    };
    int*   top_e = (int*)alloc((size_t)T_NUM * TOPK * sizeof(int));
    float* top_w = (float*)alloc((size_t)T_NUM * TOPK * sizeof(float));
    int*   offs  = (int*)alloc((E_NUM + 1) * sizeof(int));
    int*   perm  = (int*)alloc((size_t)T_NUM * TOPK * sizeof(int));
    short* xb    = (short*)alloc((size_t)T_NUM * H_DIM * 2);
    short* g_r   = (short*)alloc((size_t)T_NUM * TOPK * I_DIM * 2);
    short* u_r   = (short*)alloc((size_t)T_NUM * TOPK * I_DIM * 2);
    short* act_r = (short*)alloc((size_t)T_NUM * TOPK * I_DIM * 2);
    short* g_s   = (short*)alloc((size_t)T_NUM * SHI_DIM * 2);
    short* u_s   = (short*)alloc((size_t)T_NUM * SHI_DIM * 2);
    short* act_s = (short*)alloc((size_t)T_NUM * SHI_DIM * 2);
    short* dr    = (short*)alloc((size_t)T_NUM * TOPK * H_DIM * 2);   // 16.8 MB

    router_kernel<<<T_NUM, 256, 0, stream>>>(x, wgate, top_e, top_w, xb);
    perm_kernel<<<1, 256, 0, stream>>>(top_e, offs, perm);

    const int nmtT = T_NUM / 128;   // 8
    const int nnI  = I_DIM / 128;   // 11
    const int nnH  = H_DIM / 128;   // 16
    const int nnS  = SHI_DIM / 128; // 22

    // shared gate|up (one dispatch, nt-split): grid 8 * 44
    gemm_nb1<1><<<nmtT * (2 * nnS), 256, 0, stream>>>(
        xb, H_DIM, H_DIM, sg, su, SHI_DIM, g_s, u_s, SHI_DIM,
        nullptr, nullptr, nullptr, nmtT, 2 * nnS, nnS);
    swiglu_kernel<<<(T_NUM * SHI_DIM / 8 + 255) / 256, 256, 0, stream>>>(
        g_s, u_s, act_s, T_NUM * SHI_DIM / 8);
    // shared down: plain stores initialize all of out. grid 8 * 16
    gemm_nb1<3><<<nmtT * nnH, 256, 0, stream>>>(
        act_s, SHI_DIM, SHI_DIM, sd, nullptr, H_DIM, out, nullptr, H_DIM,
        nullptr, nullptr, nullptr, nmtT, nnH, nnH);

    // routed gate|up per expert (one dispatch): grid 8 * 22 * 16
    gemm_nb1<0><<<nmtT * (2 * nnI) * E_NUM, 256, 0, stream>>>(
        xb, H_DIM, H_DIM, wg, wu, I_DIM, g_r, u_r, I_DIM,
        perm, offs, nullptr, nmtT, 2 * nnI, nnI);
    swiglu_kernel<<<(T_NUM * TOPK * I_DIM / 8 + 255) / 256, 256, 0, stream>>>(
        g_r, u_r, act_r, T_NUM * TOPK * I_DIM / 8);
    // routed down per expert: dr[slot] = w * (act_r[slot] @ wd[e]). grid 8 * 16 * 16
    gemm_nb1<2><<<nmtT * nnH * E_NUM, 256, 0, stream>>>(
        act_r, I_DIM, I_DIM, wd, nullptr, H_DIM, dr, nullptr, H_DIM,
        perm, offs, top_w, nmtT, nnH, nnH);
    // out[t] += sum_k dr[4t+k]
    combine_kernel<<<T_NUM * H_DIM / 8 / 256, 256, 0, stream>>>(dr, out);
}

// Round 7
// 577.507 us; speedup vs baseline: 6.7911x; 6.7911x over previous
//
#include <hip/hip_runtime.h>
#include <hip/hip_bf16.h>
#include <stdint.h>

#define T_NUM 1024
#define H_DIM 2048
#define E_NUM 16
#define TOPK 4
#define I_DIM 1408
#define SHI_DIM 2816

typedef __attribute__((ext_vector_type(4))) float f32x4;
typedef __attribute__((ext_vector_type(8))) short bf16x8;
typedef __attribute__((ext_vector_type(4))) short s16x4;

static __device__ __forceinline__ short f2bf(float f) {
    __hip_bfloat16 h = __float2bfloat16(f);
    return __builtin_bit_cast(short, h);
}
static __device__ __forceinline__ float bf2f(short s) {
    return __bfloat162float(__builtin_bit_cast(__hip_bfloat16, s));
}

// ---------------- router: fp32 logits -> softmax -> top4 (+ x -> bf16) ------
__global__ void router_kernel(const float* __restrict__ x, const float* __restrict__ wgate,
                              int* __restrict__ top_e, float* __restrict__ top_w,
                              short* __restrict__ xb) {
    const int t = blockIdx.x;
    const int tid = threadIdx.x;       // 256 threads
    __shared__ float xsh[H_DIM];
    const float* xr = x + (size_t)t * H_DIM;
    for (int h = tid; h < H_DIM; h += 256) xsh[h] = xr[h];
    __syncthreads();

    {   // bf16 copy of x
        short v[8];
        #pragma unroll
        for (int i = 0; i < 8; ++i) v[i] = f2bf(xsh[tid * 8 + i]);
        *reinterpret_cast<bf16x8*>(xb + (size_t)t * H_DIM + tid * 8) = *(bf16x8*)v;
    }

    const int e = tid >> 4;            // 0..15
    const int j = tid & 15;
    const float* wr = wgate + (size_t)e * H_DIM;
    float acc = 0.f;
    for (int h = j; h < H_DIM; h += 16) acc += xsh[h] * wr[h];
    #pragma unroll
    for (int m = 8; m >= 1; m >>= 1) acc += __shfl_down(acc, m, 16);

    __shared__ float logits[E_NUM];
    if (j == 0) logits[e] = acc;
    __syncthreads();

    if (tid == 0) {
        float mx = logits[0];
        #pragma unroll
        for (int i = 1; i < E_NUM; ++i) mx = fmaxf(mx, logits[i]);
        float p[E_NUM]; float s = 0.f;
        #pragma unroll
        for (int i = 0; i < E_NUM; ++i) { p[i] = expf(logits[i] - mx); s += p[i]; }
        const float inv = 1.f / s;
        #pragma unroll
        for (int i = 0; i < E_NUM; ++i) p[i] *= inv;
        for (int k = 0; k < TOPK; ++k) {
            float best = -1.f; int bi = 0;
            #pragma unroll
            for (int i = 0; i < E_NUM; ++i) if (p[i] > best) { best = p[i]; bi = i; }
            top_e[t * TOPK + k] = bi;
            top_w[t * TOPK + k] = best;
            p[bi] = -2.f;
        }
    }
}

// ------- stable bucket sort of 4096 slots by expert (deterministic) -------
__global__ void perm_kernel(const int* __restrict__ top_e,
                            int* __restrict__ offs, int* __restrict__ perm) {
    __shared__ int cnt[256][E_NUM];
    __shared__ int base[E_NUM];
    const int tid = threadIdx.x;
    int c[E_NUM];
    #pragma unroll
    for (int i = 0; i < E_NUM; ++i) c[i] = 0;
    for (int s = tid * 16; s < tid * 16 + 16; ++s) c[top_e[s]]++;
    #pragma unroll
    for (int i = 0; i < E_NUM; ++i) cnt[tid][i] = c[i];
    __syncthreads();
    if (tid < E_NUM) {
        int run = 0;
        for (int b = 0; b < 256; ++b) { int v = cnt[b][tid]; cnt[b][tid] = run; run += v; }
        base[tid] = run;
    }
    __syncthreads();
    if (tid == 0) {
        int run = 0;
        for (int e2 = 0; e2 < E_NUM; ++e2) { int v = base[e2]; base[e2] = run; offs[e2] = run; run += v; }
        offs[E_NUM] = run;
    }
    __syncthreads();
    int run[E_NUM];
    #pragma unroll
    for (int i = 0; i < E_NUM; ++i) run[i] = base[i] + cnt[tid][i];
    for (int s = tid * 16; s < tid * 16 + 16; ++s) {
        int e2 = top_e[s];
        perm[run[e2]++] = s;
    }
}

// ------- SwiGLU combine: act = silu(g) * u  (bf16 elementwise) -------
__global__ void swiglu_kernel(const short* __restrict__ g, const short* __restrict__ u,
                              short* __restrict__ act, int n8) {
    const int i = blockIdx.x * 256 + threadIdx.x;
    if (i >= n8) return;
    bf16x8 gv = *reinterpret_cast<const bf16x8*>(g + (size_t)i * 8);
    bf16x8 uv = *reinterpret_cast<const bf16x8*>(u + (size_t)i * 8);
    short o[8];
    #pragma unroll
    for (int j = 0; j < 8; ++j) {
        float gf = bf2f(gv[j]);
        float uf = bf2f(uv[j]);
        o[j] = f2bf(gf / (1.f + __expf(-gf)) * uf);
    }
    *reinterpret_cast<bf16x8*>(act + (size_t)i * 8) = *(bf16x8*)o;
}

// ------- final combine: out[t][h] += sum_k dr[4t+k][h]  (dr pre-weighted) -------
__global__ void combine_kernel(const short* __restrict__ dr, float* __restrict__ out) {
    const int i = blockIdx.x * 256 + threadIdx.x;   // one per 8 cols of a token
    const int t = i >> 8;                            // H_DIM/8 = 256
    const int h8 = (i & 255) * 8;
    float s[8];
    f32x4 o0 = *reinterpret_cast<const f32x4*>(out + (size_t)t * H_DIM + h8);
    f32x4 o1 = *reinterpret_cast<const f32x4*>(out + (size_t)t * H_DIM + h8 + 4);
    #pragma unroll
    for (int j = 0; j < 4; ++j) { s[j] = o0[j]; s[4 + j] = o1[j]; }
    #pragma unroll
    for (int k = 0; k < TOPK; ++k) {
        bf16x8 v = *reinterpret_cast<const bf16x8*>(dr + ((size_t)(t * TOPK + k)) * H_DIM + h8);
        #pragma unroll
        for (int j = 0; j < 8; ++j) s[j] += bf2f(v[j]);
    }
    f32x4 r0 = { s[0], s[1], s[2], s[3] };
    f32x4 r1 = { s[4], s[5], s[6], s[7] };
    *reinterpret_cast<f32x4*>(out + (size_t)t * H_DIM + h8) = r0;
    *reinterpret_cast<f32x4*>(out + (size_t)t * H_DIM + h8 + 4) = r1;
}

// ---------------- GEMM: 128M x 64N tile, depth-1, 4 blocks/CU ----------------
// A: bf16 [rows][K] k-contig. B: f32 [K][N] native (inline convert).
// MODE 0: routed gate|up : A=xb gathered; ntt<nsplit ? wg[e]->Out1 : wu[e]->Out2 (bf16)
// MODE 1: shared gate|up : A=xb dense;    ntt<nsplit ? sg->Out1 : su->Out2 (bf16)
// MODE 2: routed down    : A=act_r gathered; B=wd[e]; store bf16 dr[slot] = w*v
// MODE 3: shared down    : A=act_s dense;    B=sd;    store f32 Out1[row]
template<int MODE>
__global__ __launch_bounds__(256, 4) void gemm_n64(
    const short* __restrict__ A, int lda, int Kdim,
    const float* __restrict__ B1g, const float* __restrict__ B2g, int ldb,
    void* __restrict__ Out1v, void* __restrict__ Out2v, int ldo,
    const int* __restrict__ perm, const int* __restrict__ offs,
    const float* __restrict__ top_w, int nmt, int nnt, int nsplit)
{
    constexpr int KP = 40;
    __shared__ short As[2][128 * KP];     // 20 KB
    __shared__ short Bs[2][64 * KP];      // 10 KB
    __shared__ int   rows_a[128];
    __shared__ int   rows_o[128];
    __shared__ float w_m[128];

    const int tid = threadIdx.x;

    // bijective XCD swizzle, mt innermost (mt-blocks sharing a B-strip -> same XCD L2)
    int wgid = blockIdx.x;
    {
        const int nwg = gridDim.x;
        const int qq = nwg >> 3, rr = nwg & 7;
        const int xcd = wgid & 7, lin = wgid >> 3;
        wgid = (xcd < rr ? xcd * (qq + 1) : rr * (qq + 1) + (xcd - rr) * qq) + lin;
    }
    const int mt  = wgid % nmt;
    const int ntt = (wgid / nmt) % nnt;
    const int e   = wgid / (nmt * nnt);

    int off = 0, cnt = T_NUM;
    const float* B1 = B1g;
    const float* B2 = B2g;
    if constexpr (MODE == 0) {
        off = offs[e]; cnt = offs[e + 1] - off;
        if (mt * 128 >= cnt) return;
        B1 = B1g + (size_t)e * H_DIM * I_DIM;
        B2 = B2g + (size_t)e * H_DIM * I_DIM;
    }
    if constexpr (MODE == 2) {
        off = offs[e]; cnt = offs[e + 1] - off;
        if (mt * 128 >= cnt) return;
        B1 = B1g + (size_t)e * I_DIM * H_DIM;
    }
    const float* Bsel = (ntt < nsplit) ? B1 : B2;
    const int ncol = (ntt % nsplit) * 64;

    if (tid < 128) {
        const int gm = mt * 128 + tid;
        if constexpr (MODE == 0) {
            int s = perm[off + (gm < cnt ? gm : cnt - 1)];
            rows_a[tid] = s >> 2; rows_o[tid] = s; w_m[tid] = 1.f;
        } else if constexpr (MODE == 2) {
            int s = perm[off + (gm < cnt ? gm : cnt - 1)];
            rows_a[tid] = s; rows_o[tid] = s; w_m[tid] = top_w[s];   // out row = slot
        } else {
            rows_a[tid] = gm; rows_o[tid] = gm; w_m[tid] = 1.f;
        }
    }
    __syncthreads();

    // A row indices in registers (2 rows per thread: m = it*64 + (tid>>2))
    int raReg[2];
    #pragma unroll
    for (int it = 0; it < 2; ++it) raReg[it] = rows_a[it * 64 + (tid >> 2)];

    bf16x8 aReg[2];          // A staging: 128x32 bf16 / 256thr = 2x bf16x8
    float  bReg[8];          // B staging: 64x32 f32 / 256thr = 8 floats (one n, k=kb..kb+7)

    const int bn = tid & 63;             // B column this thread stages
    const int bkb = (tid >> 6) * 8;      // B k-base (0,8,16,24)

    auto gload = [&](int kt) {
        const int k0 = kt * 32;
        #pragma unroll
        for (int it = 0; it < 2; ++it) {
            const int q = it * 256 + tid;
            const int ko = (q & 3) * 8;
            aReg[it] = *reinterpret_cast<const bf16x8*>(A + (size_t)raReg[it] * lda + k0 + ko);
        }
        const float* p1 = Bsel + (size_t)(k0 + bkb) * ldb + ncol + bn;
        #pragma unroll
        for (int dk = 0; dk < 8; ++dk) bReg[dk] = p1[(size_t)dk * ldb];
    };

    auto swrite = [&](int buf) {
        #pragma unroll
        for (int it = 0; it < 2; ++it) {
            const int q = it * 256 + tid;
            const int m = q >> 2, ko = (q & 3) * 8;
            *reinterpret_cast<bf16x8*>(&As[buf][m * KP + ko]) = aReg[it];
        }
        s16x4 v0 = { f2bf(bReg[0]), f2bf(bReg[1]), f2bf(bReg[2]), f2bf(bReg[3]) };
        s16x4 v1 = { f2bf(bReg[4]), f2bf(bReg[5]), f2bf(bReg[6]), f2bf(bReg[7]) };
        *reinterpret_cast<s16x4*>(&Bs[buf][bn * KP + bkb]) = v0;
        *reinterpret_cast<s16x4*>(&Bs[buf][bn * KP + bkb + 4]) = v1;
    };

    f32x4 acc[4][2];
    #pragma unroll
    for (int i = 0; i < 4; ++i)
        #pragma unroll
        for (int j = 0; j < 2; ++j) acc[i][j] = (f32x4)0.f;

    const int lane = tid & 63;
    const int wr = (tid >> 7), wc = (tid >> 6) & 1;   // 2x2 waves; wave out = 64Mx32N
    const int lrow = lane & 15;
    const int lko = (lane >> 4) * 8;

    auto compute = [&](int buf) {
        bf16x8 af[4];
        #pragma unroll
        for (int mi = 0; mi < 4; ++mi)
            af[mi] = *reinterpret_cast<const bf16x8*>(&As[buf][(wr * 64 + mi * 16 + lrow) * KP + lko]);
        #pragma unroll
        for (int ni = 0; ni < 2; ++ni) {
            bf16x8 bfr = *reinterpret_cast<const bf16x8*>(&Bs[buf][(wc * 32 + ni * 16 + lrow) * KP + lko]);
            #pragma unroll
            for (int mi = 0; mi < 4; ++mi)
                acc[mi][ni] = __builtin_amdgcn_mfma_f32_16x16x32_bf16(af[mi], bfr, acc[mi][ni], 0, 0, 0);
        }
    };

    const int NK = Kdim / 32;
    gload(0);
    int cur = 0;
    for (int kt = 0; kt < NK; ++kt) {
        swrite(cur);
        __syncthreads();
        if (kt + 1 < NK) gload(kt + 1);
        compute(cur);
        cur ^= 1;
    }

    // epilogue
    #pragma unroll
    for (int mi = 0; mi < 4; ++mi) {
        #pragma unroll
        for (int j = 0; j < 4; ++j) {
            const int ml = wr * 64 + mi * 16 + (lane >> 4) * 4 + j;
            const int gm = mt * 128 + ml;
            if constexpr (MODE == 0 || MODE == 2) { if (gm >= cnt) continue; }
            const int orow = (MODE == 0 || MODE == 2) ? rows_o[ml] : gm;
            const float wsc = w_m[ml];
            #pragma unroll
            for (int ni = 0; ni < 2; ++ni) {
                const int n = ncol + wc * 32 + ni * 16 + (lane & 15);
                const float v = acc[mi][ni][j];
                if constexpr (MODE == 0 || MODE == 1) {
                    short* o = (short*)((ntt < nsplit) ? Out1v : Out2v);
                    o[(size_t)orow * ldo + n] = f2bf(v);
                } else if constexpr (MODE == 2) {
                    ((short*)Out1v)[(size_t)orow * ldo + n] = f2bf(v * wsc);
                } else {
                    ((float*)Out1v)[(size_t)orow * ldo + n] = v;
                }
            }
        }
    }
}

extern "C" void kernel_launch(void* const* d_in, const int* in_sizes, int n_in,
                              void* d_out, int out_size, void* d_ws, size_t ws_size,
                              hipStream_t stream) {
    const float* x     = (const float*)d_in[0];
    const float* wgate = (const float*)d_in[1];
    const float* wg    = (const float*)d_in[2];
    const float* wu    = (const float*)d_in[3];
    const float* wd    = (const float*)d_in[4];
    const float* sg    = (const float*)d_in[5];
    const float* su    = (const float*)d_in[6];
    const float* sd    = (const float*)d_in[7];
    float* out = (float*)d_out;

    uintptr_t p = (uintptr_t)d_ws;
    auto alloc = [&](size_t bytes) {
        p = (p + 255) & ~(uintptr_t)255;
        void* r = (void*)p; p += bytes; return r;
    };
    int*   top_e = (int*)alloc((size_t)T_NUM * TOPK * sizeof(int));
    float* top_w = (float*)alloc((size_t)T_NUM * TOPK * sizeof(float));
    int*   offs  = (int*)alloc((E_NUM + 1) * sizeof(int));
    int*   perm  = (int*)alloc((size_t)T_NUM * TOPK * sizeof(int));
    short* xb    = (short*)alloc((size_t)T_NUM * H_DIM * 2);
    short* g_r   = (short*)alloc((size_t)T_NUM * TOPK * I_DIM * 2);
    short* u_r   = (short*)alloc((size_t)T_NUM * TOPK * I_DIM * 2);
    short* act_r = (short*)alloc((size_t)T_NUM * TOPK * I_DIM * 2);
    short* g_s   = (short*)alloc((size_t)T_NUM * SHI_DIM * 2);
    short* u_s   = (short*)alloc((size_t)T_NUM * SHI_DIM * 2);
    short* act_s = (short*)alloc((size_t)T_NUM * SHI_DIM * 2);
    short* dr    = (short*)alloc((size_t)T_NUM * TOPK * H_DIM * 2);   // 16.8 MB

    router_kernel<<<T_NUM, 256, 0, stream>>>(x, wgate, top_e, top_w, xb);
    perm_kernel<<<1, 256, 0, stream>>>(top_e, offs, perm);

    const int nmtT = T_NUM / 128;    // 8
    const int nnI  = I_DIM / 64;     // 22
    const int nnH  = H_DIM / 64;     // 32
    const int nnS  = SHI_DIM / 64;   // 44

    // shared gate|up (one dispatch, nt-split): grid 8 * 88
    gemm_n64<1><<<nmtT * (2 * nnS), 256, 0, stream>>>(
        xb, H_DIM, H_DIM, sg, su, SHI_DIM, g_s, u_s, SHI_DIM,
        nullptr, nullptr, nullptr, nmtT, 2 * nnS, nnS);
    swiglu_kernel<<<(T_NUM * SHI_DIM / 8 + 255) / 256, 256, 0, stream>>>(
        g_s, u_s, act_s, T_NUM * SHI_DIM / 8);
    // shared down: plain stores initialize all of out. grid 8 * 32
    gemm_n64<3><<<nmtT * nnH, 256, 0, stream>>>(
        act_s, SHI_DIM, SHI_DIM, sd, nullptr, H_DIM, out, nullptr, H_DIM,
        nullptr, nullptr, nullptr, nmtT, nnH, nnH);

    // routed gate|up per expert (one dispatch): grid 8 * 44 * 16
    gemm_n64<0><<<nmtT * (2 * nnI) * E_NUM, 256, 0, stream>>>(
        xb, H_DIM, H_DIM, wg, wu, I_DIM, g_r, u_r, I_DIM,
        perm, offs, nullptr, nmtT, 2 * nnI, nnI);
    swiglu_kernel<<<(T_NUM * TOPK * I_DIM / 8 + 255) / 256, 256, 0, stream>>>(
        g_r, u_r, act_r, T_NUM * TOPK * I_DIM / 8);
    // routed down per expert: dr[slot] = w * (act_r[slot] @ wd[e]). grid 8 * 32 * 16
    gemm_n64<2><<<nmtT * nnH * E_NUM, 256, 0, stream>>>(
        act_r, I_DIM, I_DIM, wd, nullptr, H_DIM, dr, nullptr, H_DIM,
        perm, offs, top_w, nmtT, nnH, nnH);
    // out[t] += sum_k dr[4t+k]
    combine_kernel<<<T_NUM * H_DIM / 8 / 256, 256, 0, stream>>>(dr, out);
}